// Round 1
// baseline (459.541 us; speedup 1.0000x reference)
//
#include <hip/hip_runtime.h>

#define DD 256   // feature dim
#define CC 100   // num classes

// Workspace layout (bytes):
//   [0, 102400)        : g_sums  (CC*DD floats)
//   [102400, 102800)   : g_counts (CC floats)
//   [102800, 102808)   : g_sumsq (1 double)
#define WS_SUMS_OFF   0
#define WS_COUNTS_OFF (CC * DD * sizeof(float))
#define WS_SUMSQ_OFF  (CC * DD * sizeof(float) + CC * sizeof(float))
#define WS_TOTAL      (WS_SUMSQ_OFF + sizeof(double))

__global__ __launch_bounds__(1024) void affinity_pass1(
        const float* __restrict__ feats,
        const float* __restrict__ labels,
        float* __restrict__ g_sums,
        float* __restrict__ g_counts,
        double* __restrict__ g_sumsq,
        int N)
{
    __shared__ float s_sums[CC * DD];   // 100 KB
    __shared__ float s_counts[CC];

    for (int i = threadIdx.x; i < CC * DD; i += blockDim.x) s_sums[i] = 0.f;
    for (int i = threadIdx.x; i < CC; i += blockDim.x)      s_counts[i] = 0.f;
    __syncthreads();

    const int lane = threadIdx.x & 63;
    const int wid  = threadIdx.x >> 6;
    const int wpb  = blockDim.x >> 6;
    const long long gw = (long long)blockIdx.x * wpb + wid;
    const long long nw = (long long)gridDim.x * wpb;

    float sumsq = 0.f;

    for (long long row = gw; row < N; row += nw) {
        // ---- argmax over the 100-element label row (first-max semantics) ----
        const float* lrow = labels + row * (long long)CC;
        float v   = lrow[lane];
        int   idx = lane;
        if (lane < CC - 64) {                    // lanes 0..35 read elems 64..99
            float v1 = lrow[64 + lane];
            if (v1 > v) { v = v1; idx = 64 + lane; }   // lower idx wins ties
        }
        #pragma unroll
        for (int off = 1; off < 64; off <<= 1) {
            float ov = __shfl_xor(v, off);
            int   oi = __shfl_xor(idx, off);
            if (ov > v || (ov == v && oi < idx)) { v = ov; idx = oi; }
        }
        const int cls = idx;                     // uniform across the wave

        // ---- feature row: 4 coalesced stride-64 loads ----
        const float* frow = feats + row * (long long)DD;
        float f0 = frow[lane];
        float f1 = frow[lane + 64];
        float f2 = frow[lane + 128];
        float f3 = frow[lane + 192];
        sumsq += f0 * f0 + f1 * f1 + f2 * f2 + f3 * f3;

        // LDS bank = lane % 32 -> 2-way aliasing only (free)
        atomicAdd(&s_sums[cls * DD + lane      ], f0);
        atomicAdd(&s_sums[cls * DD + lane + 64 ], f1);
        atomicAdd(&s_sums[cls * DD + lane + 128], f2);
        atomicAdd(&s_sums[cls * DD + lane + 192], f3);
        if (lane == 0) atomicAdd(&s_counts[cls], 1.0f);
    }

    // ---- sum of squares: wave reduce -> one f64 atomic per wave ----
    #pragma unroll
    for (int off = 1; off < 64; off <<= 1) sumsq += __shfl_xor(sumsq, off);
    if (lane == 0) atomicAdd(g_sumsq, (double)sumsq);

    __syncthreads();
    // ---- flush block-local class sums to global ----
    for (int i = threadIdx.x; i < CC * DD; i += blockDim.x) {
        float s = s_sums[i];
        if (s != 0.f) atomicAdd(&g_sums[i], s);
    }
    for (int i = threadIdx.x; i < CC; i += blockDim.x) {
        float s = s_counts[i];
        if (s != 0.f) atomicAdd(&g_counts[i], s);
    }
}

__global__ __launch_bounds__(256) void affinity_finalize(
        const float* __restrict__ g_sums,
        const float* __restrict__ g_counts,
        const double* __restrict__ g_sumsq,
        float* __restrict__ out)
{
    const int d = threadIdx.x;   // one thread per feature dim (DD == 256)

    double colsum = 0.0, s2 = 0.0, dot = 0.0, cc = 0.0;
    for (int c = 0; c < CC; ++c) {
        float  cnt = g_counts[c];
        float  s   = g_sums[c * DD + d];
        double center = (cnt > 0.f ? (double)s / (double)cnt : 0.0) + 1e-6;
        colsum += center;
        s2     += center * center;
        dot    += center * (double)s;
        cc     += (double)cnt * center * center;
    }
    // sum over (c,d) of (center - colmean)^2, this column's share:
    double interp = s2 - colsum * colsum / (double)CC;

    __shared__ double red0[256], red1[256], red2[256];
    red0[d] = dot; red1[d] = cc; red2[d] = interp;
    __syncthreads();
    for (int off = 128; off > 0; off >>= 1) {
        if (d < off) {
            red0[d] += red0[d + off];
            red1[d] += red1[d + off];
            red2[d] += red2[d + off];
        }
        __syncthreads();
    }
    if (d == 0) {
        double intra = *g_sumsq - 2.0 * red0[0] + red1[0];
        double inter = red2[0] / (double)CC;
        out[0] = (float)(intra / (inter + 1e-6));
    }
}

extern "C" void kernel_launch(void* const* d_in, const int* in_sizes, int n_in,
                              void* d_out, int out_size, void* d_ws, size_t ws_size,
                              hipStream_t stream)
{
    const float* feats  = (const float*)d_in[0];
    const float* labels = (const float*)d_in[1];
    const int N = in_sizes[0] / DD;

    float*  g_sums   = (float*)((char*)d_ws + WS_SUMS_OFF);
    float*  g_counts = (float*)((char*)d_ws + WS_COUNTS_OFF);
    double* g_sumsq  = (double*)((char*)d_ws + WS_SUMSQ_OFF);

    hipMemsetAsync(d_ws, 0, WS_TOTAL, stream);

    affinity_pass1<<<256, 1024, 0, stream>>>(feats, labels, g_sums, g_counts,
                                             g_sumsq, N);
    affinity_finalize<<<1, 256, 0, stream>>>(g_sums, g_counts, g_sumsq,
                                             (float*)d_out);
}

// Round 2
// 444.760 us; speedup vs baseline: 1.0332x; 1.0332x over previous
//
#include <hip/hip_runtime.h>
#include <math.h>

#define DD 256   // feature dim
#define CC 100   // num classes
#define RB 4     // rows per wave-iteration (batched for MLP)

// Workspace layout (bytes):
//   [0, 102400)        : g_sums  (CC*DD floats)
//   [102400, 102800)   : g_counts (CC floats)
//   [102800, 102808)   : g_sumsq (1 double)
#define WS_SUMS_OFF   0
#define WS_COUNTS_OFF (CC * DD * sizeof(float))
#define WS_SUMSQ_OFF  (CC * DD * sizeof(float) + CC * sizeof(float))
#define WS_TOTAL      (WS_SUMSQ_OFF + sizeof(double))

__global__ __launch_bounds__(1024) void affinity_pass1(
        const float* __restrict__ feats,
        const float* __restrict__ labels,
        float* __restrict__ g_sums,
        float* __restrict__ g_counts,
        double* __restrict__ g_sumsq,
        int N)
{
    __shared__ float s_sums[CC * DD];   // 100 KB -> 1 block/CU
    __shared__ float s_counts[CC];

    for (int i = threadIdx.x; i < CC * DD; i += blockDim.x) s_sums[i] = 0.f;
    for (int i = threadIdx.x; i < CC; i += blockDim.x)      s_counts[i] = 0.f;
    __syncthreads();

    const int lane = threadIdx.x & 63;
    const int wid  = threadIdx.x >> 6;
    const int wpb  = blockDim.x >> 6;
    const long long gw = (long long)blockIdx.x * wpb + wid;
    const long long nw = (long long)gridDim.x * wpb;

    float sumsq = 0.f;

    for (long long base = gw * RB; base < N; base += nw * RB) {
        // ---------- phase 1: issue ALL loads (independent -> MLP) ----------
        float lv0[RB], lv1[RB];
        float f[RB][4];
        bool  ok[RB];
        #pragma unroll
        for (int r = 0; r < RB; ++r) {
            const long long row = base + r;
            ok[r] = (row < N);
            const long long rr = ok[r] ? row : (long long)(N - 1);
            const float* lrow = labels + rr * (long long)CC;
            lv0[r] = lrow[lane];
            lv1[r] = (lane < CC - 64) ? lrow[64 + lane] : -INFINITY;
            const float* frow = feats + rr * (long long)DD;
            #pragma unroll
            for (int j = 0; j < 4; ++j)
                f[r][j] = frow[lane + 64 * j];
        }

        // ---------- phase 2: 4 independent argmax shuffle chains ----------
        int cls[RB];
        #pragma unroll
        for (int r = 0; r < RB; ++r) {
            float v   = lv0[r];
            int   idx = lane;
            if (lv1[r] > v) { v = lv1[r]; idx = 64 + lane; }  // lower idx wins ties
            #pragma unroll
            for (int off = 1; off < 64; off <<= 1) {
                float ov = __shfl_xor(v, off);
                int   oi = __shfl_xor(idx, off);
                if (ov > v || (ov == v && oi < idx)) { v = ov; idx = oi; }
            }
            cls[r] = idx;                    // uniform across the wave
        }

        // ---------- phase 3: sumsq + LDS accumulation ----------
        #pragma unroll
        for (int r = 0; r < RB; ++r) {
            if (!ok[r]) continue;
            float s = 0.f;
            #pragma unroll
            for (int j = 0; j < 4; ++j) s += f[r][j] * f[r][j];
            sumsq += s;
            // LDS bank = lane % 32 -> 2-way aliasing only (free)
            #pragma unroll
            for (int j = 0; j < 4; ++j)
                atomicAdd(&s_sums[cls[r] * DD + lane + 64 * j], f[r][j]);
            if (lane == 0) atomicAdd(&s_counts[cls[r]], 1.0f);
        }
    }

    // ---- sum of squares: wave reduce -> one f64 atomic per wave ----
    #pragma unroll
    for (int off = 1; off < 64; off <<= 1) sumsq += __shfl_xor(sumsq, off);
    if (lane == 0) atomicAdd(g_sumsq, (double)sumsq);

    __syncthreads();
    // ---- flush block-local class sums to global ----
    for (int i = threadIdx.x; i < CC * DD; i += blockDim.x) {
        float s = s_sums[i];
        if (s != 0.f) atomicAdd(&g_sums[i], s);
    }
    for (int i = threadIdx.x; i < CC; i += blockDim.x) {
        float s = s_counts[i];
        if (s != 0.f) atomicAdd(&g_counts[i], s);
    }
}

__global__ __launch_bounds__(256) void affinity_finalize(
        const float* __restrict__ g_sums,
        const float* __restrict__ g_counts,
        const double* __restrict__ g_sumsq,
        float* __restrict__ out)
{
    const int d = threadIdx.x;   // one thread per feature dim (DD == 256)

    double colsum = 0.0, s2 = 0.0, dot = 0.0, cc = 0.0;
    for (int c = 0; c < CC; ++c) {
        float  cnt = g_counts[c];
        float  s   = g_sums[c * DD + d];
        double center = (cnt > 0.f ? (double)s / (double)cnt : 0.0) + 1e-6;
        colsum += center;
        s2     += center * center;
        dot    += center * (double)s;
        cc     += (double)cnt * center * center;
    }
    // sum over (c,d) of (center - colmean)^2, this column's share:
    double interp = s2 - colsum * colsum / (double)CC;

    __shared__ double red0[256], red1[256], red2[256];
    red0[d] = dot; red1[d] = cc; red2[d] = interp;
    __syncthreads();
    for (int off = 128; off > 0; off >>= 1) {
        if (d < off) {
            red0[d] += red0[d + off];
            red1[d] += red1[d + off];
            red2[d] += red2[d + off];
        }
        __syncthreads();
    }
    if (d == 0) {
        double intra = *g_sumsq - 2.0 * red0[0] + red1[0];
        double inter = red2[0] / (double)CC;
        out[0] = (float)(intra / (inter + 1e-6));
    }
}

extern "C" void kernel_launch(void* const* d_in, const int* in_sizes, int n_in,
                              void* d_out, int out_size, void* d_ws, size_t ws_size,
                              hipStream_t stream)
{
    const float* feats  = (const float*)d_in[0];
    const float* labels = (const float*)d_in[1];
    const int N = in_sizes[0] / DD;

    float*  g_sums   = (float*)((char*)d_ws + WS_SUMS_OFF);
    float*  g_counts = (float*)((char*)d_ws + WS_COUNTS_OFF);
    double* g_sumsq  = (double*)((char*)d_ws + WS_SUMSQ_OFF);

    hipMemsetAsync(d_ws, 0, WS_TOTAL, stream);

    affinity_pass1<<<256, 1024, 0, stream>>>(feats, labels, g_sums, g_counts,
                                             g_sumsq, N);
    affinity_finalize<<<1, 256, 0, stream>>>(g_sums, g_counts, g_sumsq,
                                             (float*)d_out);
}

// Round 3
// 418.705 us; speedup vs baseline: 1.0975x; 1.0622x over previous
//
#include <hip/hip_runtime.h>

#define DD  256    // feature dim
#define CC  100    // num classes
#define TPB 1024   // threads per block (16 waves)
#define RPB 1024   // rows per block

// Workspace layout (bytes):
//   [0, 102400)          : g_sums    (CC*DD f32)  -- reduce output / atomic fallback
//   [102400, 102800)     : g_counts  (CC int)
//   [102800, 102808)     : g_sumsq   (1 double)
//   [103424, ...)        : g_partials (nblocks * CC*DD f32)
#define WS_SUMS_OFF   0
#define WS_COUNTS_OFF (CC * DD * 4)
#define WS_SUMSQ_OFF  (WS_COUNTS_OFF + CC * 4)
#define WS_HDR        (WS_SUMSQ_OFF + 8)
#define WS_PART_OFF   103424

__global__ __launch_bounds__(TPB) void affinity_pass1(
        const float* __restrict__ feats,
        const float* __restrict__ labels,
        float* __restrict__ g_sums,
        int*   __restrict__ g_counts,
        double* __restrict__ g_sumsq,
        float* __restrict__ g_partials,
        int use_partials,
        int N)
{
    __shared__ float  s_sums[CC * DD];   // 100 KB
    __shared__ int    s_cls[RPB];
    __shared__ int    s_cnt[CC];
    __shared__ double s_red[16];

    const int tid = threadIdx.x;
    for (int i = tid; i < CC * DD; i += TPB) s_sums[i] = 0.f;
    if (tid < CC) s_cnt[tid] = 0;
    __syncthreads();

    const long long block_base = (long long)blockIdx.x * RPB;

    // ---------------- phase A: one thread per row, register argmax ----------
    {
        const long long row = block_base + tid;
        int cls = -1;
        if (row < (long long)N) {
            const float4* l4 = (const float4*)(labels + row * (long long)CC);
            float best = -3.4e38f;
            int   bi   = 0;
            #pragma unroll
            for (int j = 0; j < CC / 4; ++j) {      // 25 independent float4 loads
                float4 q = l4[j];
                if (q.x > best) { best = q.x; bi = 4 * j; }
                if (q.y > best) { best = q.y; bi = 4 * j + 1; }
                if (q.z > best) { best = q.z; bi = 4 * j + 2; }
                if (q.w > best) { best = q.w; bi = 4 * j + 3; }
            }
            cls = bi;
            atomicAdd(&s_cnt[cls], 1);              // native int LDS atomic
        }
        s_cls[tid] = cls;
    }
    __syncthreads();

    // ---------------- phase B: wave per row, native ds_add_f32 --------------
    const int lane  = tid & 63;
    const int wid   = tid >> 6;
    const int wbase = wid * 64;                     // rows [wbase, wbase+64)
    float sumsq = 0.f;

    for (int g = 0; g < 16; ++g) {
        const int r0 = wbase + g * 4;
        const int4 c4 = *(const int4*)&s_cls[r0];   // broadcast ds_read_b128
        const int cls_[4] = { c4.x, c4.y, c4.z, c4.w };

        float f[4][4];
        #pragma unroll
        for (int r = 0; r < 4; ++r) {
            long long row = block_base + r0 + r;
            if (row >= (long long)N) row = (long long)N - 1;   // clamp (guarded below)
            const float* frow = feats + row * (long long)DD;
            #pragma unroll
            for (int j = 0; j < 4; ++j)
                f[r][j] = frow[lane + 64 * j];
        }

        #pragma unroll
        for (int r = 0; r < 4; ++r) {
            if (cls_[r] < 0) continue;
            float* srow = &s_sums[cls_[r] * DD + lane];
            #pragma unroll
            for (int j = 0; j < 4; ++j) {
                const float v = f[r][j];
                sumsq += v * v;
                unsafeAtomicAdd(srow + 64 * j, v);  // ds_add_f32, no return chain
            }
        }
    }

    // ---------------- sumsq: wave reduce -> block reduce -> 1 f64 atomic ----
    double ds = (double)sumsq;
    #pragma unroll
    for (int off = 1; off < 64; off <<= 1) ds += __shfl_xor(ds, off);
    if (lane == 0) s_red[wid] = ds;
    __syncthreads();   // also guarantees all ds_add_f32 complete (lgkmcnt drain)
    if (tid == 0) {
        double t = 0.0;
        #pragma unroll
        for (int i = 0; i < 16; ++i) t += s_red[i];
        atomicAdd(g_sumsq, t);                      // 1 per block
    }

    // ---------------- flush ------------------------------------------------
    if (use_partials) {
        float* dst = g_partials + (size_t)blockIdx.x * (CC * DD);
        for (int i = tid; i < CC * DD; i += TPB) dst[i] = s_sums[i];
    } else {
        for (int i = tid; i < CC * DD; i += TPB) {
            const float s = s_sums[i];
            if (s != 0.f) unsafeAtomicAdd(&g_sums[i], s);
        }
    }
    if (tid < CC) {
        const int c = s_cnt[tid];
        if (c) atomicAdd(&g_counts[tid], c);        // native int global atomic
    }
}

__global__ __launch_bounds__(DD) void affinity_reduce(
        const float* __restrict__ g_partials,
        float* __restrict__ g_sums,
        int nblocks)
{
    const int c = blockIdx.x;          // class
    const int d = threadIdx.x;         // dim
    const float* p = g_partials + c * DD + d;
    double acc = 0.0;
    #pragma unroll 8
    for (int b = 0; b < nblocks; ++b)
        acc += (double)p[(size_t)b * (CC * DD)];   // coalesced across threads
    g_sums[c * DD + d] = (float)acc;
}

__global__ __launch_bounds__(DD) void affinity_finalize(
        const float* __restrict__ g_sums,
        const int*   __restrict__ g_counts,
        const double* __restrict__ g_sumsq,
        float* __restrict__ out)
{
    const int d = threadIdx.x;         // one thread per feature dim

    double colsum = 0.0, s2 = 0.0, dot = 0.0, cc = 0.0;
    for (int c = 0; c < CC; ++c) {
        const int    cnt = g_counts[c];
        const float  s   = g_sums[c * DD + d];
        const double center = (cnt > 0 ? (double)s / (double)cnt : 0.0) + 1e-6;
        colsum += center;
        s2     += center * center;
        dot    += center * (double)s;
        cc     += (double)cnt * center * center;
    }
    double interp = s2 - colsum * colsum / (double)CC;

    __shared__ double red0[DD], red1[DD], red2[DD];
    red0[d] = dot; red1[d] = cc; red2[d] = interp;
    __syncthreads();
    for (int off = DD / 2; off > 0; off >>= 1) {
        if (d < off) {
            red0[d] += red0[d + off];
            red1[d] += red1[d + off];
            red2[d] += red2[d + off];
        }
        __syncthreads();
    }
    if (d == 0) {
        const double intra = *g_sumsq - 2.0 * red0[0] + red1[0];
        const double inter = red2[0] / (double)CC;
        out[0] = (float)(intra / (inter + 1e-6));
    }
}

extern "C" void kernel_launch(void* const* d_in, const int* in_sizes, int n_in,
                              void* d_out, int out_size, void* d_ws, size_t ws_size,
                              hipStream_t stream)
{
    const float* feats  = (const float*)d_in[0];
    const float* labels = (const float*)d_in[1];
    const int N = in_sizes[0] / DD;
    const int nblocks = (N + RPB - 1) / RPB;       // 256 for N=262144

    float*  g_sums     = (float*)((char*)d_ws + WS_SUMS_OFF);
    int*    g_counts   = (int*)((char*)d_ws + WS_COUNTS_OFF);
    double* g_sumsq    = (double*)((char*)d_ws + WS_SUMSQ_OFF);
    float*  g_partials = (float*)((char*)d_ws + WS_PART_OFF);

    const size_t need = (size_t)WS_PART_OFF + (size_t)nblocks * (CC * DD) * 4;
    const int use_partials = (ws_size >= need) ? 1 : 0;

    hipMemsetAsync(d_ws, 0, WS_HDR, stream);

    affinity_pass1<<<nblocks, TPB, 0, stream>>>(feats, labels, g_sums, g_counts,
                                                g_sumsq, g_partials, use_partials, N);
    if (use_partials)
        affinity_reduce<<<CC, DD, 0, stream>>>(g_partials, g_sums, nblocks);
    affinity_finalize<<<1, DD, 0, stream>>>(g_sums, g_counts, g_sumsq,
                                            (float*)d_out);
}